// Round 12
// baseline (493.591 us; speedup 1.0000x reference)
//
#include <hip/hip_runtime.h>

#define NN 100000
#define NE 800000
#define NG 128
#define U  128
#define NGIN 3
#define NBUCK 64
#define NPB 1563                 // ceil(NN / NBUCK)
#define ACHUNK 4096
#define NAB ((NE + ACHUNK - 1) / ACHUNK)   // 196 phase-A blocks
#define TPITCH 288               // LDS tile row pitch (bytes), padded vs 256

typedef short bf16x8 __attribute__((ext_vector_type(8)));
typedef float f32x4 __attribute__((ext_vector_type(4)));

__device__ __forceinline__ unsigned short f2b(float f) {
    union { float f; unsigned u; } v; v.f = f;
    unsigned r = v.u + 0x7FFF + ((v.u >> 16) & 1);   // RNE
    return (unsigned short)(r >> 16);
}
__device__ __forceinline__ float blo(unsigned u) {
    union { unsigned u; float f; } v; v.u = u << 16; return v.f;
}
__device__ __forceinline__ float bhi(unsigned u) {
    union { unsigned u; float f; } v; v.u = u & 0xffff0000u; return v.f;
}
__device__ __forceinline__ unsigned cvtpk(float lo, float hi) {
    unsigned r;
    asm("v_cvt_pk_bf16_f32 %0, %1, %2" : "=v"(r) : "v"(lo), "v"(hi));
    return r;
}

// ---------------------------------------------------------------------------
// x (fp32) -> hb (bf16)
// ---------------------------------------------------------------------------
__global__ __launch_bounds__(256) void convert_k(const float* __restrict__ x,
                                                 unsigned short* __restrict__ hb) {
    int i = blockIdx.x * 256 + threadIdx.x;
    if (i >= NN * U / 4) return;
    float4 v = reinterpret_cast<const float4*>(x)[i];
    uint2 o;
    o.x = (unsigned)f2b(v.x) | ((unsigned)f2b(v.y) << 16);
    o.y = (unsigned)f2b(v.z) | ((unsigned)f2b(v.w) << 16);
    reinterpret_cast<uint2*>(hb)[i] = o;
}

// ---------------------------------------------------------------------------
// pack W (fp32 [k][c]) into MFMA fragment order (bf16):
// frag[((t*4+ks)*64+lane)*8+j] = W[ks*32+8*(lane>>4)+j][t*16+(lane&15)]
// = B-frag of W = A-frag of W^T (same bits)
// ---------------------------------------------------------------------------
__global__ __launch_bounds__(256) void wfrag_k(const float* __restrict__ W1,
                                               const float* __restrict__ W2,
                                               unsigned short* __restrict__ wfrag) {
    int b = blockIdx.x;
    const float* src = ((b & 1) ? W2 : W1) + (size_t)(b >> 1) * U * U;
    unsigned short* dst = wfrag + (size_t)b * 16384;
    for (int e = threadIdx.x; e < 16384; e += 256) {
        int j = e & 7, lane = (e >> 3) & 63, ks = (e >> 9) & 3, ct = e >> 11;
        int k = ks * 32 + ((lane >> 4) << 3) + j;
        int c = ct * 16 + (lane & 15);
        dst[e] = f2b(src[k * U + c]);
    }
}

// bn epilogue precompute: scl = gamma*rsqrt(var+eps); sh = (b2-mean)*scl+beta
__global__ __launch_bounds__(128) void bnprep_k(const float* __restrict__ b2,
                                                const float* __restrict__ gam,
                                                const float* __restrict__ bet,
                                                const float* __restrict__ mean,
                                                const float* __restrict__ var,
                                                float* __restrict__ scl,
                                                float* __restrict__ sh) {
    int i = blockIdx.x * 128 + threadIdx.x;
    float s = gam[i] * rsqrtf(var[i] + 1e-3f);
    scl[i] = s;
    sh[i] = (b2[i] - mean[i]) * s + bet[i];
}

// ---------------------------------------------------------------------------
// CSR build, owner-computes (bhist -> bscan -> phaseA -> phaseB)
// ---------------------------------------------------------------------------
__global__ __launch_bounds__(256) void bhist_k(const int* __restrict__ ei,
                                               int* __restrict__ bcnt) {
    __shared__ int lh[NBUCK];
    int tid = threadIdx.x;
    if (tid < NBUCK) lh[tid] = 0;
    __syncthreads();
    int e0 = blockIdx.x * ACHUNK;
    int eend = min(e0 + ACHUNK, NE);
    for (int e = e0 + tid; e < eend; e += 256)
        atomicAdd(&lh[ei[e] / NPB], 1);
    __syncthreads();
    if (tid < NBUCK && lh[tid]) atomicAdd(&bcnt[tid], lh[tid]);
}

__global__ __launch_bounds__(64) void bscan_k(const int* __restrict__ bcnt,
                                              int* __restrict__ bcur,
                                              int* __restrict__ boff,
                                              int* __restrict__ rowptr) {
    int lane = threadIdx.x;
    int v = bcnt[lane];
    int incl = v;
#pragma unroll
    for (int off = 1; off < 64; off <<= 1) {
        int n = __shfl_up(incl, off);
        if (lane >= off) incl += n;
    }
    int excl = incl - v;
    bcur[lane] = excl;
    boff[lane] = excl;
    if (lane == 63) { boff[64] = incl; rowptr[NN] = NE; }
}

__global__ __launch_bounds__(256) void phaseA_k(const int* __restrict__ ei,
                                                const float* __restrict__ ew,
                                                int* __restrict__ bcur,
                                                uint2* __restrict__ tmp) {
    __shared__ int lh[NBUCK];
    int tid = threadIdx.x;
    if (tid < NBUCK) lh[tid] = 0;
    __syncthreads();
    int e0 = blockIdx.x * ACHUNK;
    int eend = min(e0 + ACHUNK, NE);
    for (int e = e0 + tid; e < eend; e += 256)
        atomicAdd(&lh[ei[e] / NPB], 1);
    __syncthreads();
    if (tid < NBUCK) {
        int c = lh[tid];
        lh[tid] = c ? atomicAdd(&bcur[tid], c) : 0;
    }
    __syncthreads();
    for (int e = e0 + tid; e < eend; e += 256) {
        int d = ei[e];
        int pos = atomicAdd(&lh[d / NPB], 1);
        uint2 r;
        r.x = ((unsigned)ei[NE + e] << 15) | (unsigned)f2b(ew[e]);
        r.y = (unsigned)d;
        tmp[pos] = r;
    }
}

__global__ __launch_bounds__(256) void phaseB_k(const uint2* __restrict__ tmp,
                                                const int* __restrict__ boff,
                                                int* __restrict__ rowptr,
                                                unsigned* __restrict__ esw) {
    __shared__ int cnt[1792];
    __shared__ int ws[4];
    const int tid = threadIdx.x;
    const int b = blockIdx.x;
    const int n0 = b * NPB;
    const int npb = min(NPB, NN - n0);
    const int wbeg = boff[b], wend = boff[b + 1];

    for (int i = tid; i < 1792; i += 256) cnt[i] = 0;
    __syncthreads();
    for (int e = wbeg + tid; e < wend; e += 256)
        atomicAdd(&cnt[(int)tmp[e].y - n0], 1);
    __syncthreads();
    int base = tid * 7;
    int v[7]; int s = 0;
#pragma unroll
    for (int k = 0; k < 7; ++k) { v[k] = cnt[base + k]; s += v[k]; }
    int lane = tid & 63, wid = tid >> 6;
    int incl = s;
#pragma unroll
    for (int off = 1; off < 64; off <<= 1) {
        int n = __shfl_up(incl, off);
        if (lane >= off) incl += n;
    }
    if (lane == 63) ws[wid] = incl;
    __syncthreads();
    if (tid == 0) {
        int a = 0;
#pragma unroll
        for (int w = 0; w < 4; ++w) { int t = ws[w]; ws[w] = a; a += t; }
    }
    __syncthreads();
    int run = wbeg + ws[wid] + (incl - s);
#pragma unroll
    for (int k = 0; k < 7; ++k) { cnt[base + k] = run; run += v[k]; }
    __syncthreads();
    for (int i = tid; i < npb; i += 256) rowptr[n0 + i] = cnt[i];
    __syncthreads();
    for (int e = wbeg + tid; e < wend; e += 256) {
        uint2 r = tmp[e];
        int pos = atomicAdd(&cnt[(int)r.y - n0], 1);
        esw[pos] = r.x;
    }
}

// ---------------------------------------------------------------------------
// gather: z[n] = 1.5*h[n] + sum h[src]*w ; unroll x8, 8 row loads in flight
// ---------------------------------------------------------------------------
__global__ __launch_bounds__(256) void gather_k(const unsigned short* __restrict__ h,
                                                const unsigned* __restrict__ esw,
                                                const int* __restrict__ rowptr,
                                                unsigned short* __restrict__ z) {
    int node = blockIdx.x * 4 + (threadIdx.x >> 6);
    if (node >= NN) return;
    int lane = threadIdx.x & 63;
    const unsigned* hp = reinterpret_cast<const unsigned*>(h);
    int beg = rowptr[node], end = rowptr[node + 1];

    float ax[8], ay[8];
#pragma unroll
    for (int k = 0; k < 8; ++k) { ax[k] = 0.f; ay[k] = 0.f; }

    for (int cb = beg; cb < end; cb += 64) {
        int n = min(end - cb, 64);
        unsigned rec = (lane < n) ? esw[cb + lane] : 0u;   // pad: src 0, w +0.0
        int sv = (int)(rec >> 15);
        float wv = __uint_as_float((rec & 0x7FFFu) << 16);
        for (int i = 0; i < n; i += 8) {
            int s_[8]; float w_[8]; unsigned h_[8];
#pragma unroll
            for (int k = 0; k < 8; ++k) {
                s_[k] = __shfl(sv, i + k);
                w_[k] = __shfl(wv, i + k);
            }
#pragma unroll
            for (int k = 0; k < 8; ++k)
                h_[k] = hp[(size_t)s_[k] * 64 + lane];
#pragma unroll
            for (int k = 0; k < 8; ++k) {
                ax[k] = fmaf(blo(h_[k]), w_[k], ax[k]);
                ay[k] = fmaf(bhi(h_[k]), w_[k], ay[k]);
            }
        }
    }
    float axs = ((ax[0] + ax[1]) + (ax[2] + ax[3])) + ((ax[4] + ax[5]) + (ax[6] + ax[7]));
    float ays = ((ay[0] + ay[1]) + (ay[2] + ay[3])) + ((ay[4] + ay[5]) + (ay[6] + ay[7]));
    unsigned hn = hp[(size_t)node * 64 + lane];
    axs = fmaf(1.5f, blo(hn), axs);
    ays = fmaf(1.5f, bhi(hn), ays);
    reinterpret_cast<unsigned*>(z)[(size_t)node * 64 + lane] =
        (unsigned)f2b(axs) | ((unsigned)f2b(ays) << 16);
}

// ---------------------------------------------------------------------------
// fused dense, TRANSPOSED form: one 16-row strip per wave.
//   z1^T = mfma(W1^T-frag, z-A-frag)   -> thread (c,g) holds z1[c][4 consec cols]
//   ep1: relu + 2 cvt_pk -> one 8B LDS write per ct (wave-private padded tile)
//   b2-frags = ds_read_b128 from tile (z1 in A-layout)
//   h^T  = mfma(W2^T-frag, b2)         -> thread holds h[c][4 consec cols]
//   ep2: bn(fma)+relu + 2 cvt_pk -> one 8B coalesced store; pooled shfl+atomics
// ---------------------------------------------------------------------------
__global__ __launch_bounds__(256) void fused_dense_k(const unsigned short* __restrict__ z,
                                                     const unsigned short* __restrict__ wf1,
                                                     const unsigned short* __restrict__ wf2,
                                                     const float* __restrict__ bias1,
                                                     const float* __restrict__ sclp,
                                                     const float* __restrict__ shp,
                                                     const int* __restrict__ gidx,
                                                     unsigned short* __restrict__ outp,
                                                     float* __restrict__ pooled,
                                                     int pool_off) {
    __shared__ char lds[4][16 * TPITCH];     // 4 wave-private tiles, 4.5KB each
    const int lane = threadIdx.x & 63;
    const int wid = threadIdx.x >> 6;
    const int c = lane & 15;                 // node-within-strip
    const int g = lane >> 4;                 // col/k group
    const int strip = blockIdx.x * 4 + wid;
    const bool valid = (strip * 16 < NN);    // NN%16==0: strip all-valid or not
    const int r0 = valid ? strip * 16 : 0;
    char* myl = lds[wid];

    // z A-frags: lane holds z[r0+c][8g + j + 32ks]
    bf16x8 zf[4];
    const size_t zb = (size_t)(r0 + c) * U + (g << 3);
#pragma unroll
    for (int ks = 0; ks < 4; ++ks)
        zf[ks] = *reinterpret_cast<const bf16x8*>(z + zb + ks * 32);

    // ---- m1: z1^T ----
    f32x4 acc1[8];
#pragma unroll
    for (int ct = 0; ct < 8; ++ct) acc1[ct] = (f32x4){0.f, 0.f, 0.f, 0.f};
#pragma unroll
    for (int ct = 0; ct < 8; ++ct)
#pragma unroll
        for (int ks = 0; ks < 4; ++ks) {
            bf16x8 w = *reinterpret_cast<const bf16x8*>(
                wf1 + (((ct * 4 + ks) * 64 + lane) << 3));
            acc1[ct] = __builtin_amdgcn_mfma_f32_16x16x32_bf16(w, zf[ks], acc1[ct], 0, 0, 0);
        }

    // ep1: relu + pack + 8B LDS write; tile[node c][col ct*16+g*4 .. +3]
#pragma unroll
    for (int ct = 0; ct < 8; ++ct) {
        float4 bv = *reinterpret_cast<const float4*>(bias1 + ct * 16 + (g << 2));
        float v0 = fmaxf(acc1[ct][0] + bv.x, 0.f);
        float v1 = fmaxf(acc1[ct][1] + bv.y, 0.f);
        float v2 = fmaxf(acc1[ct][2] + bv.z, 0.f);
        float v3 = fmaxf(acc1[ct][3] + bv.w, 0.f);
        uint2 pk;
        pk.x = cvtpk(v0, v1);
        pk.y = cvtpk(v2, v3);
        *reinterpret_cast<uint2*>(myl + c * TPITCH + ct * 32 + g * 8) = pk;
    }
    asm volatile("s_waitcnt lgkmcnt(0)" ::: "memory");
    __builtin_amdgcn_sched_barrier(0);

    // b2-frags: lane reads z1[node c][8g + 32ks .. +8] (16B contiguous)
    bf16x8 b2[4];
#pragma unroll
    for (int ks = 0; ks < 4; ++ks)
        b2[ks] = *reinterpret_cast<const bf16x8*>(myl + c * TPITCH + g * 16 + ks * 64);

    // ---- m2: h^T ----
    f32x4 acc2[8];
#pragma unroll
    for (int ct = 0; ct < 8; ++ct) acc2[ct] = (f32x4){0.f, 0.f, 0.f, 0.f};
#pragma unroll
    for (int ct = 0; ct < 8; ++ct)
#pragma unroll
        for (int ks = 0; ks < 4; ++ks) {
            bf16x8 w = *reinterpret_cast<const bf16x8*>(
                wf2 + (((ct * 4 + ks) * 64 + lane) << 3));
            acc2[ct] = __builtin_amdgcn_mfma_f32_16x16x32_bf16(w, b2[ks], acc2[ct], 0, 0, 0);
        }

    // ---- ep2: bn + relu -> h, pooled ----
    const int row = r0 + c;
    int ga = gidx[r0], gb = gidx[r0 + 15];
    bool uni = (ga == gb);
    int myg = uni ? ga : gidx[row];
#pragma unroll
    for (int ct = 0; ct < 8; ++ct) {
        int hc = ct * 16 + (g << 2);
        float4 s4 = *reinterpret_cast<const float4*>(sclp + hc);
        float4 h4 = *reinterpret_cast<const float4*>(shp + hc);
        float v0 = fmaxf(fmaf(acc2[ct][0], s4.x, h4.x), 0.f);
        float v1 = fmaxf(fmaf(acc2[ct][1], s4.y, h4.y), 0.f);
        float v2 = fmaxf(fmaf(acc2[ct][2], s4.z, h4.z), 0.f);
        float v3 = fmaxf(fmaf(acc2[ct][3], s4.w, h4.w), 0.f);
        if (valid) {
            uint2 pk;
            pk.x = cvtpk(v0, v1);
            pk.y = cvtpk(v2, v3);
            *reinterpret_cast<uint2*>(outp + (size_t)row * U + hc) = pk;
        }
        if (uni) {
            float p0 = v0, p1 = v1, p2 = v2, p3 = v3;
#pragma unroll
            for (int m = 1; m <= 8; m <<= 1) {
                p0 += __shfl_xor(p0, m);
                p1 += __shfl_xor(p1, m);
                p2 += __shfl_xor(p2, m);
                p3 += __shfl_xor(p3, m);
            }
            if (valid && c == 0) {
                float* pp = &pooled[(size_t)ga * (NGIN * U) + pool_off + hc];
                unsafeAtomicAdd(pp + 0, p0);
                unsafeAtomicAdd(pp + 1, p1);
                unsafeAtomicAdd(pp + 2, p2);
                unsafeAtomicAdd(pp + 3, p3);
            }
        } else if (valid) {
            float* pp = &pooled[(size_t)myg * (NGIN * U) + pool_off + hc];
            unsafeAtomicAdd(pp + 0, v0);
            unsafeAtomicAdd(pp + 1, v1);
            unsafeAtomicAdd(pp + 2, v2);
            unsafeAtomicAdd(pp + 3, v3);
        }
    }
}

// ---------------------------------------------------------------------------
// readout MLPs (fp32, tiny)
// ---------------------------------------------------------------------------
__global__ __launch_bounds__(128) void mlp1_k(const float* __restrict__ pooled,
                                              const float* __restrict__ Wm1,
                                              const float* __restrict__ bm1,
                                              float* __restrict__ g) {
    __shared__ float sp[NGIN * U];
    int gi = blockIdx.x, c = threadIdx.x;
    for (int j = c; j < NGIN * U; j += 128) sp[j] = pooled[(size_t)gi * (NGIN * U) + j];
    __syncthreads();
    float acc = bm1[c];
    for (int k = 0; k < NGIN * U; ++k) acc = fmaf(sp[k], Wm1[(size_t)k * 128 + c], acc);
    g[gi * 128 + c] = fmaxf(acc, 0.f);
}

__global__ __launch_bounds__(256) void mlp2_k(const float* __restrict__ g,
                                              const float* __restrict__ Wm2,
                                              const float* __restrict__ bm2,
                                              float* __restrict__ out) {
    int idx = blockIdx.x * 256 + threadIdx.x;
    int gi = idx >> 4, c = idx & 15;
    float acc = bm2[c];
    for (int k = 0; k < 128; ++k) acc = fmaf(g[gi * 128 + k], Wm2[k * 16 + c], acc);
    out[gi * 16 + c] = acc;
}

extern "C" void kernel_launch(void* const* d_in, const int* in_sizes, int n_in,
                              void* d_out, int out_size, void* d_ws, size_t ws_size,
                              hipStream_t stream) {
    const float* x   = (const float*)d_in[0];
    const int*   ei  = (const int*)d_in[1];
    const float* ew  = (const float*)d_in[2];
    const int*   gix = (const int*)d_in[3];
    const float* W1  = (const float*)d_in[4];
    const float* b1  = (const float*)d_in[5];
    const float* W2  = (const float*)d_in[6];
    const float* b2  = (const float*)d_in[7];
    const float* gam = (const float*)d_in[8];
    const float* bet = (const float*)d_in[9];
    const float* bmn = (const float*)d_in[10];
    const float* bvr = (const float*)d_in[11];
    const float* Wm1 = (const float*)d_in[12];
    const float* bm1 = (const float*)d_in[13];
    const float* Wm2 = (const float*)d_in[14];
    const float* bm2 = (const float*)d_in[15];
    float* out = (float*)d_out;

    unsigned short* hb = (unsigned short*)d_ws;
    unsigned short* z  = hb + (size_t)NN * U;
    float* pooled = (float*)(z + (size_t)NN * U);
    float* gbuf   = pooled + (size_t)NG * (NGIN * U);
    unsigned short* wfrag = (unsigned short*)(gbuf + (size_t)NG * 128);
    unsigned* esw = (unsigned*)(wfrag + 6 * 16384);
    uint2* tmp    = (uint2*)(esw + NE);
    int*   rowptr = (int*)(tmp + NE);
    int*   bcnt   = rowptr + (NN + 1);
    int*   bcur   = bcnt + NBUCK;
    int*   boff   = bcur + NBUCK;
    float* sclp   = (float*)(boff + NBUCK + 1);
    float* shp    = sclp + NGIN * U;

    convert_k<<<(NN * U / 4 + 255) / 256, 256, 0, stream>>>(x, hb);
    hipMemsetAsync(bcnt, 0, NBUCK * sizeof(int), stream);
    bhist_k<<<NAB, 256, 0, stream>>>(ei, bcnt);
    bscan_k<<<1, 64, 0, stream>>>(bcnt, bcur, boff, rowptr);
    phaseA_k<<<NAB, 256, 0, stream>>>(ei, ew, bcur, tmp);
    phaseB_k<<<NBUCK, 256, 0, stream>>>(tmp, boff, rowptr, esw);
    wfrag_k<<<6, 256, 0, stream>>>(W1, W2, wfrag);
    bnprep_k<<<NGIN, 128, 0, stream>>>(b2, gam, bet, bmn, bvr, sclp, shp);
    hipMemsetAsync(pooled, 0, (size_t)NG * (NGIN * U) * sizeof(float), stream);

    const int dense_grid = (NN / 16 + 3) / 4;   // 1 strip/wave, 4 waves/block
    for (int i = 0; i < NGIN; ++i) {
        gather_k<<<NN / 4, 256, 0, stream>>>(hb, esw, rowptr, z);
        fused_dense_k<<<dense_grid, 256, 0, stream>>>(
            z, wfrag + (size_t)(2 * i) * 16384, wfrag + (size_t)(2 * i + 1) * 16384,
            b1 + i * U, sclp + i * U, shp + i * U,
            gix, hb, pooled, i * U);
    }
    mlp1_k<<<NG, 128, 0, stream>>>(pooled, Wm1, bm1, gbuf);
    mlp2_k<<<(NG * 16) / 256, 256, 0, stream>>>(gbuf, Wm2, bm2, out);
}

// Round 13
// 288.123 us; speedup vs baseline: 1.7131x; 1.7131x over previous
//
#include <hip/hip_runtime.h>

#define NN 100000
#define NE 800000
#define NG 128
#define U  128
#define NGIN 3
#define NBUCK 64
#define NPB 1563                 // ceil(NN / NBUCK)
#define ACHUNK 4096
#define NAB ((NE + ACHUNK - 1) / ACHUNK)   // 196 phase-A blocks
#define ZP 136                   // tile pitch in bf16 (272B: 16B-aligned, conflict-even)

typedef short bf16x8 __attribute__((ext_vector_type(8)));
typedef float f32x4 __attribute__((ext_vector_type(4)));

__device__ __forceinline__ unsigned short f2b(float f) {
    union { float f; unsigned u; } v; v.f = f;
    unsigned r = v.u + 0x7FFF + ((v.u >> 16) & 1);   // RNE
    return (unsigned short)(r >> 16);
}
__device__ __forceinline__ float blo(unsigned u) {
    union { unsigned u; float f; } v; v.u = u << 16; return v.f;
}
__device__ __forceinline__ float bhi(unsigned u) {
    union { unsigned u; float f; } v; v.u = u & 0xffff0000u; return v.f;
}
__device__ __forceinline__ unsigned cvtpk(float lo, float hi) {
    unsigned r;
    asm("v_cvt_pk_bf16_f32 %0, %1, %2" : "=v"(r) : "v"(lo), "v"(hi));
    return r;
}

// ---------------------------------------------------------------------------
// x (fp32) -> hb (bf16)
// ---------------------------------------------------------------------------
__global__ __launch_bounds__(256) void convert_k(const float* __restrict__ x,
                                                 unsigned short* __restrict__ hb) {
    int i = blockIdx.x * 256 + threadIdx.x;
    if (i >= NN * U / 4) return;
    float4 v = reinterpret_cast<const float4*>(x)[i];
    uint2 o;
    o.x = (unsigned)f2b(v.x) | ((unsigned)f2b(v.y) << 16);
    o.y = (unsigned)f2b(v.z) | ((unsigned)f2b(v.w) << 16);
    reinterpret_cast<uint2*>(hb)[i] = o;
}

// ---------------------------------------------------------------------------
// pack W (fp32 [k][c]) into MFMA B-fragment order (bf16)
// ---------------------------------------------------------------------------
__global__ __launch_bounds__(256) void wfrag_k(const float* __restrict__ W1,
                                               const float* __restrict__ W2,
                                               unsigned short* __restrict__ wfrag) {
    int b = blockIdx.x;
    const float* src = ((b & 1) ? W2 : W1) + (size_t)(b >> 1) * U * U;
    unsigned short* dst = wfrag + (size_t)b * 16384;
    for (int e = threadIdx.x; e < 16384; e += 256) {
        int j = e & 7, lane = (e >> 3) & 63, ks = (e >> 9) & 3, ct = e >> 11;
        int k = ks * 32 + ((lane >> 4) << 3) + j;
        int c = ct * 16 + (lane & 15);
        dst[e] = f2b(src[k * U + c]);
    }
}

// bn epilogue precompute: scl = gamma*rsqrt(var+eps); sh = (b2-mean)*scl+beta
__global__ __launch_bounds__(128) void bnprep_k(const float* __restrict__ b2,
                                                const float* __restrict__ gam,
                                                const float* __restrict__ bet,
                                                const float* __restrict__ mean,
                                                const float* __restrict__ var,
                                                float* __restrict__ scl,
                                                float* __restrict__ sh) {
    int i = blockIdx.x * 128 + threadIdx.x;
    float s = gam[i] * rsqrtf(var[i] + 1e-3f);
    scl[i] = s;
    sh[i] = (b2[i] - mean[i]) * s + bet[i];
}

// ---------------------------------------------------------------------------
// CSR build, owner-computes (bhist -> bscan -> phaseA -> phaseB)
// ---------------------------------------------------------------------------
__global__ __launch_bounds__(256) void bhist_k(const int* __restrict__ ei,
                                               int* __restrict__ bcnt) {
    __shared__ int lh[NBUCK];
    int tid = threadIdx.x;
    if (tid < NBUCK) lh[tid] = 0;
    __syncthreads();
    int e0 = blockIdx.x * ACHUNK;
    int eend = min(e0 + ACHUNK, NE);
    for (int e = e0 + tid; e < eend; e += 256)
        atomicAdd(&lh[ei[e] / NPB], 1);
    __syncthreads();
    if (tid < NBUCK && lh[tid]) atomicAdd(&bcnt[tid], lh[tid]);
}

__global__ __launch_bounds__(64) void bscan_k(const int* __restrict__ bcnt,
                                              int* __restrict__ bcur,
                                              int* __restrict__ boff,
                                              int* __restrict__ rowptr) {
    int lane = threadIdx.x;
    int v = bcnt[lane];
    int incl = v;
#pragma unroll
    for (int off = 1; off < 64; off <<= 1) {
        int n = __shfl_up(incl, off);
        if (lane >= off) incl += n;
    }
    int excl = incl - v;
    bcur[lane] = excl;
    boff[lane] = excl;
    if (lane == 63) { boff[64] = incl; rowptr[NN] = NE; }
}

__global__ __launch_bounds__(256) void phaseA_k(const int* __restrict__ ei,
                                                const float* __restrict__ ew,
                                                int* __restrict__ bcur,
                                                uint2* __restrict__ tmp) {
    __shared__ int lh[NBUCK];
    int tid = threadIdx.x;
    if (tid < NBUCK) lh[tid] = 0;
    __syncthreads();
    int e0 = blockIdx.x * ACHUNK;
    int eend = min(e0 + ACHUNK, NE);
    for (int e = e0 + tid; e < eend; e += 256)
        atomicAdd(&lh[ei[e] / NPB], 1);
    __syncthreads();
    if (tid < NBUCK) {
        int c = lh[tid];
        lh[tid] = c ? atomicAdd(&bcur[tid], c) : 0;
    }
    __syncthreads();
    for (int e = e0 + tid; e < eend; e += 256) {
        int d = ei[e];
        int pos = atomicAdd(&lh[d / NPB], 1);
        uint2 r;
        r.x = ((unsigned)ei[NE + e] << 15) | (unsigned)f2b(ew[e]);
        r.y = (unsigned)d;
        tmp[pos] = r;
    }
}

__global__ __launch_bounds__(256) void phaseB_k(const uint2* __restrict__ tmp,
                                                const int* __restrict__ boff,
                                                int* __restrict__ rowptr,
                                                unsigned* __restrict__ esw) {
    __shared__ int cnt[1792];
    __shared__ int ws[4];
    const int tid = threadIdx.x;
    const int b = blockIdx.x;
    const int n0 = b * NPB;
    const int npb = min(NPB, NN - n0);
    const int wbeg = boff[b], wend = boff[b + 1];

    for (int i = tid; i < 1792; i += 256) cnt[i] = 0;
    __syncthreads();
    for (int e = wbeg + tid; e < wend; e += 256)
        atomicAdd(&cnt[(int)tmp[e].y - n0], 1);
    __syncthreads();
    int base = tid * 7;
    int v[7]; int s = 0;
#pragma unroll
    for (int k = 0; k < 7; ++k) { v[k] = cnt[base + k]; s += v[k]; }
    int lane = tid & 63, wid = tid >> 6;
    int incl = s;
#pragma unroll
    for (int off = 1; off < 64; off <<= 1) {
        int n = __shfl_up(incl, off);
        if (lane >= off) incl += n;
    }
    if (lane == 63) ws[wid] = incl;
    __syncthreads();
    if (tid == 0) {
        int a = 0;
#pragma unroll
        for (int w = 0; w < 4; ++w) { int t = ws[w]; ws[w] = a; a += t; }
    }
    __syncthreads();
    int run = wbeg + ws[wid] + (incl - s);
#pragma unroll
    for (int k = 0; k < 7; ++k) { cnt[base + k] = run; run += v[k]; }
    __syncthreads();
    for (int i = tid; i < npb; i += 256) rowptr[n0 + i] = cnt[i];
    __syncthreads();
    for (int e = wbeg + tid; e < wend; e += 256) {
        uint2 r = tmp[e];
        int pos = atomicAdd(&cnt[(int)r.y - n0], 1);
        esw[pos] = r.x;
    }
}

// ---------------------------------------------------------------------------
// fused gather + 2x matmul per layer. Block = one 16-node strip, 4 waves.
//  phase 1: wave w gathers rows 4w..4w+3 -> zt (z = 1.5h + sum h[src]*w)
//  phase 2: m1 ct-split (wave w -> ct {2w,2w+1}), ep1 -> z1t
//  phase 3: m2 ct-split, ep2 (bn fma + relu) -> hout + pooled atomics
// h double-buffered across layers (gather reads hin while ep2 writes hout).
// ---------------------------------------------------------------------------
__global__ __launch_bounds__(256) void fusedgd_k(const unsigned short* __restrict__ hin,
                                                 const unsigned* __restrict__ esw,
                                                 const int* __restrict__ rowptr,
                                                 const unsigned short* __restrict__ wf1,
                                                 const unsigned short* __restrict__ wf2,
                                                 const float* __restrict__ bias1,
                                                 const float* __restrict__ sclp,
                                                 const float* __restrict__ shp,
                                                 const int* __restrict__ gidx,
                                                 unsigned short* __restrict__ hout,
                                                 float* __restrict__ pooled,
                                                 int pool_off) {
    __shared__ unsigned short zt[16 * ZP];    // 4352B: z tile
    __shared__ unsigned short z1t[16 * ZP];   // 4352B: z1 tile
    const int tid = threadIdx.x;
    const int lane = tid & 63;
    const int wid = tid >> 6;
    const int r0 = blockIdx.x * 16;           // NN % 16 == 0: all strips full
    const unsigned* hp = reinterpret_cast<const unsigned*>(hin);
    unsigned* ztd = reinterpret_cast<unsigned*>(zt);

    // ---- phase 1: gather 4 rows per wave ----
    for (int q = 0; q < 4; ++q) {
        int row = wid * 4 + q;
        int node = r0 + row;
        int beg = rowptr[node], end = rowptr[node + 1];
        float ax[8], ay[8];
#pragma unroll
        for (int k = 0; k < 8; ++k) { ax[k] = 0.f; ay[k] = 0.f; }
        for (int cb = beg; cb < end; cb += 64) {
            int n = min(end - cb, 64);
            unsigned rec = (lane < n) ? esw[cb + lane] : 0u;   // pad: src 0, w 0
            int sv = (int)(rec >> 15);
            float wv = __uint_as_float((rec & 0x7FFFu) << 16);
            for (int i = 0; i < n; i += 8) {
                int s_[8]; float w_[8]; unsigned h_[8];
#pragma unroll
                for (int k = 0; k < 8; ++k) {
                    s_[k] = __shfl(sv, i + k);
                    w_[k] = __shfl(wv, i + k);
                }
#pragma unroll
                for (int k = 0; k < 8; ++k)
                    h_[k] = hp[(size_t)s_[k] * 64 + lane];
#pragma unroll
                for (int k = 0; k < 8; ++k) {
                    ax[k] = fmaf(blo(h_[k]), w_[k], ax[k]);
                    ay[k] = fmaf(bhi(h_[k]), w_[k], ay[k]);
                }
            }
        }
        float axs = ((ax[0] + ax[1]) + (ax[2] + ax[3])) + ((ax[4] + ax[5]) + (ax[6] + ax[7]));
        float ays = ((ay[0] + ay[1]) + (ay[2] + ay[3])) + ((ay[4] + ay[5]) + (ay[6] + ay[7]));
        unsigned hn = hp[(size_t)node * 64 + lane];
        axs = fmaf(1.5f, blo(hn), axs);
        ays = fmaf(1.5f, bhi(hn), ays);
        ztd[row * (ZP / 2) + lane] = cvtpk(axs, ays);   // cols 2*lane, 2*lane+1
    }
    __syncthreads();

    // ---- phase 2: m1, wave handles ct in {2wid, 2wid+1} ----
    const int c = lane & 15;
    const int g = lane >> 4;
    bf16x8 a1[4];
#pragma unroll
    for (int ks = 0; ks < 4; ++ks)
        a1[ks] = *reinterpret_cast<const bf16x8*>(zt + c * ZP + ks * 32 + g * 8);

    f32x4 acc1[2];
    acc1[0] = (f32x4){0.f, 0.f, 0.f, 0.f};
    acc1[1] = (f32x4){0.f, 0.f, 0.f, 0.f};
#pragma unroll
    for (int t = 0; t < 2; ++t) {
        int ct = wid * 2 + t;
#pragma unroll
        for (int ks = 0; ks < 4; ++ks) {
            bf16x8 b = *reinterpret_cast<const bf16x8*>(
                wf1 + (((ct * 4 + ks) * 64 + lane) << 3));
            acc1[t] = __builtin_amdgcn_mfma_f32_16x16x32_bf16(a1[ks], b, acc1[t], 0, 0, 0);
        }
    }
    // ep1: relu -> z1t  (C/D: col = ct*16+c, row = g*4+j)
#pragma unroll
    for (int t = 0; t < 2; ++t) {
        int col = (wid * 2 + t) * 16 + c;
        float bv = bias1[col];
#pragma unroll
        for (int j = 0; j < 4; ++j) {
            int row = g * 4 + j;
            z1t[row * ZP + col] = f2b(fmaxf(acc1[t][j] + bv, 0.f));
        }
    }
    __syncthreads();

    // ---- phase 3: m2 ----
    bf16x8 a2[4];
#pragma unroll
    for (int ks = 0; ks < 4; ++ks)
        a2[ks] = *reinterpret_cast<const bf16x8*>(z1t + c * ZP + ks * 32 + g * 8);

    f32x4 acc2[2];
    acc2[0] = (f32x4){0.f, 0.f, 0.f, 0.f};
    acc2[1] = (f32x4){0.f, 0.f, 0.f, 0.f};
#pragma unroll
    for (int t = 0; t < 2; ++t) {
        int ct = wid * 2 + t;
#pragma unroll
        for (int ks = 0; ks < 4; ++ks) {
            bf16x8 b = *reinterpret_cast<const bf16x8*>(
                wf2 + (((ct * 4 + ks) * 64 + lane) << 3));
            acc2[t] = __builtin_amdgcn_mfma_f32_16x16x32_bf16(a2[ks], b, acc2[t], 0, 0, 0);
        }
    }

    // ep2: bn + relu -> hout, pooled
    int ga = gidx[r0], gb = gidx[r0 + 15];
    bool uni = (ga == gb);
#pragma unroll
    for (int t = 0; t < 2; ++t) {
        int col = (wid * 2 + t) * 16 + c;
        float scl = sclp[col], sh = shp[col];
        float hv[4];
        float psum = 0.f;
#pragma unroll
        for (int j = 0; j < 4; ++j) {
            int row = g * 4 + j;
            float v = fmaxf(fmaf(acc2[t][j], scl, sh), 0.f);
            hv[j] = v;
            psum += v;
            hout[(size_t)(r0 + row) * U + col] = f2b(v);
        }
        if (uni) {
            psum += __shfl_xor(psum, 16);
            psum += __shfl_xor(psum, 32);
            if (lane < 16)
                unsafeAtomicAdd(&pooled[(size_t)ga * (NGIN * U) + pool_off + col], psum);
        } else {
#pragma unroll
            for (int j = 0; j < 4; ++j)
                unsafeAtomicAdd(&pooled[(size_t)gidx[r0 + g * 4 + j] * (NGIN * U) + pool_off + col], hv[j]);
        }
    }
}

// ---------------------------------------------------------------------------
// readout MLPs (fp32, tiny)
// ---------------------------------------------------------------------------
__global__ __launch_bounds__(128) void mlp1_k(const float* __restrict__ pooled,
                                              const float* __restrict__ Wm1,
                                              const float* __restrict__ bm1,
                                              float* __restrict__ g) {
    __shared__ float sp[NGIN * U];
    int gi = blockIdx.x, c = threadIdx.x;
    for (int j = c; j < NGIN * U; j += 128) sp[j] = pooled[(size_t)gi * (NGIN * U) + j];
    __syncthreads();
    float acc = bm1[c];
    for (int k = 0; k < NGIN * U; ++k) acc = fmaf(sp[k], Wm1[(size_t)k * 128 + c], acc);
    g[gi * 128 + c] = fmaxf(acc, 0.f);
}

__global__ __launch_bounds__(256) void mlp2_k(const float* __restrict__ g,
                                              const float* __restrict__ Wm2,
                                              const float* __restrict__ bm2,
                                              float* __restrict__ out) {
    int idx = blockIdx.x * 256 + threadIdx.x;
    int gi = idx >> 4, c = idx & 15;
    float acc = bm2[c];
    for (int k = 0; k < 128; ++k) acc = fmaf(g[gi * 128 + k], Wm2[k * 16 + c], acc);
    out[gi * 16 + c] = acc;
}

extern "C" void kernel_launch(void* const* d_in, const int* in_sizes, int n_in,
                              void* d_out, int out_size, void* d_ws, size_t ws_size,
                              hipStream_t stream) {
    const float* x   = (const float*)d_in[0];
    const int*   ei  = (const int*)d_in[1];
    const float* ew  = (const float*)d_in[2];
    const int*   gix = (const int*)d_in[3];
    const float* W1  = (const float*)d_in[4];
    const float* b1  = (const float*)d_in[5];
    const float* W2  = (const float*)d_in[6];
    const float* b2  = (const float*)d_in[7];
    const float* gam = (const float*)d_in[8];
    const float* bet = (const float*)d_in[9];
    const float* bmn = (const float*)d_in[10];
    const float* bvr = (const float*)d_in[11];
    const float* Wm1 = (const float*)d_in[12];
    const float* bm1 = (const float*)d_in[13];
    const float* Wm2 = (const float*)d_in[14];
    const float* bm2 = (const float*)d_in[15];
    float* out = (float*)d_out;

    // workspace: hb0, hb1 bf16 [NN*U] | pooled f32 | g f32 | wfrag bf16 [6*16384] |
    // esw u32 [NE] | tmp uint2 [NE] | rowptr [NN+1] | bcnt | bcur | boff | scl | sh
    unsigned short* hb0 = (unsigned short*)d_ws;
    unsigned short* hb1 = hb0 + (size_t)NN * U;
    float* pooled = (float*)(hb1 + (size_t)NN * U);
    float* gbuf   = pooled + (size_t)NG * (NGIN * U);
    unsigned short* wfrag = (unsigned short*)(gbuf + (size_t)NG * 128);
    unsigned* esw = (unsigned*)(wfrag + 6 * 16384);
    uint2* tmp    = (uint2*)(esw + NE);
    int*   rowptr = (int*)(tmp + NE);
    int*   bcnt   = rowptr + (NN + 1);
    int*   bcur   = bcnt + NBUCK;
    int*   boff   = bcur + NBUCK;
    float* sclp   = (float*)(boff + NBUCK + 1);
    float* shp    = sclp + NGIN * U;

    convert_k<<<(NN * U / 4 + 255) / 256, 256, 0, stream>>>(x, hb0);
    hipMemsetAsync(bcnt, 0, NBUCK * sizeof(int), stream);
    bhist_k<<<NAB, 256, 0, stream>>>(ei, bcnt);
    bscan_k<<<1, 64, 0, stream>>>(bcnt, bcur, boff, rowptr);
    phaseA_k<<<NAB, 256, 0, stream>>>(ei, ew, bcur, tmp);
    phaseB_k<<<NBUCK, 256, 0, stream>>>(tmp, boff, rowptr, esw);
    wfrag_k<<<6, 256, 0, stream>>>(W1, W2, wfrag);
    bnprep_k<<<NGIN, 128, 0, stream>>>(b2, gam, bet, bmn, bvr, sclp, shp);
    hipMemsetAsync(pooled, 0, (size_t)NG * (NGIN * U) * sizeof(float), stream);

    unsigned short* hA = hb0;
    unsigned short* hB = hb1;
    for (int i = 0; i < NGIN; ++i) {
        fusedgd_k<<<NN / 16, 256, 0, stream>>>(
            hA, esw, rowptr,
            wfrag + (size_t)(2 * i) * 16384, wfrag + (size_t)(2 * i + 1) * 16384,
            b1 + i * U, sclp + i * U, shp + i * U,
            gix, hB, pooled, i * U);
        unsigned short* t = hA; hA = hB; hB = t;
    }
    mlp1_k<<<NG, 128, 0, stream>>>(pooled, Wm1, bm1, gbuf);
    mlp2_k<<<(NG * 16) / 256, 256, 0, stream>>>(gbuf, Wm2, bm2, out);
}